// Round 15
// baseline (699.287 us; speedup 1.0000x reference)
//
#include <hip/hip_runtime.h>
#include <hip/hip_bf16.h>
#include <hip/hip_fp16.h>
#include <math.h>

#define NFAC 100000
#define NCOMP 4000
#define NEDGE 500000
#define NB 256
#define DF 1536
#define DC 27
#define H 128
#define EDIM 10
#define EDIMP 16  // padded EF row (64B, aligned vector loads)

typedef __attribute__((ext_vector_type(8))) short short8v;
typedef __attribute__((ext_vector_type(4))) float f32x4;

#define GLOAD_LDS16(g, l)                                                              \
  __builtin_amdgcn_global_load_lds((const __attribute__((address_space(1))) unsigned int*)(g), \
                                   (__attribute__((address_space(3))) unsigned int*)(l), 16, 0, 0)

__device__ __forceinline__ float group32_sum(float v) {
#pragma unroll
  for (int m = 16; m > 0; m >>= 1) v += __shfl_xor(v, m);
  return v;
}

__device__ __forceinline__ unsigned short bf16rn(float x) {
  unsigned int u = __float_as_uint(x);
  unsigned int r = (u + 0x7fffu + ((u >> 16) & 1u)) >> 16;
  return (unsigned short)r;
}
__device__ __forceinline__ float bf16tof(unsigned short h) {
  return __uint_as_float(((unsigned int)h) << 16);
}

// ---------------- edge features, written in CSR order (POS[e] from k_scatter) ----------------
__global__ void k_edge_feat(const float* __restrict__ ea, const float* __restrict__ lamp,
                            const int* __restrict__ pos, float* __restrict__ ef) {
  int e = blockIdx.x * blockDim.x + threadIdx.x;
  if (e >= NEDGE) return;
  float s   = fminf(fmaxf(ea[2 * e], -1.f), 1.f);
  float dec = fminf(fmaxf(ea[2 * e + 1], 0.f), 1.f);
  float lam = fmaxf(lamp[0], 1e-6f);
  float dt  = -logf(fmaxf(dec, 1e-6f)) / lam;
  float t   = log1pf(fmaxf(dt, 0.f)) * (1.f / 30.f);
  float* o = ef + (size_t)pos[e] * EDIMP;
  o[0] = s;
  o[1] = dec;
#pragma unroll
  for (int k = 1; k < 8; k++) o[1 + k] = __sinf(t * (float)k);
  o[9] = t;
  o[10] = 0.f; o[11] = 0.f; o[12] = 0.f; o[13] = 0.f; o[14] = 0.f; o[15] = 0.f;
}

// ---------------- CSR build ----------------
__global__ void k_hist(const int* __restrict__ dst, int* __restrict__ deg) {
  int e = blockIdx.x * blockDim.x + threadIdx.x;
  if (e < NEDGE) atomicAdd(&deg[dst[e]], 1);
}

__global__ __launch_bounds__(1024) void k_scan(const int* __restrict__ deg, int* __restrict__ off) {
  __shared__ int s[4096];
  int t = threadIdx.x;
  for (int i = t; i < 4096; i += 1024) s[i] = (i < NCOMP) ? deg[i] : 0;
  __syncthreads();
  for (int d = 1; d < 4096; d <<= 1) {
    int vals[4];
#pragma unroll
    for (int j = 0; j < 4; j++) {
      int i = t + j * 1024;
      vals[j] = (i >= d) ? s[i - d] : 0;
    }
    __syncthreads();
#pragma unroll
    for (int j = 0; j < 4; j++) {
      int i = t + j * 1024;
      s[i] += vals[j];
    }
    __syncthreads();
  }
  for (int i = t; i < 4096; i += 1024) off[i + 1] = s[i];
  if (t == 0) off[0] = 0;
}

// scatter: build srcs[] in CSR order and record POS[e] for edge-feature placement
__global__ void k_scatter(const int* __restrict__ dst, const int* __restrict__ src,
                          const int* __restrict__ off, int* __restrict__ cur,
                          int* __restrict__ pos, int* __restrict__ srcs) {
  int e = blockIdx.x * blockDim.x + threadIdx.x;
  if (e < NEDGE) {
    int d = dst[e];
    int p = atomicAdd(&cur[d], 1);
    int slot = off[d] + p;
    pos[e] = slot;
    srcs[slot] = src[e];
  }
}

// ---------------- weight preconvert: W[K][128] fp32 -> Bt_hi/Bt_lo [128][K] bf16 ----------------
__global__ void k_conv_w(const float* __restrict__ W, unsigned short* __restrict__ Bh,
                         unsigned short* __restrict__ Bl, int K) {
  int i = blockIdx.x * blockDim.x + threadIdx.x;
  if (i >= K * H) return;
  int k = i >> 7, c = i & 127;
  float x = W[i];
  unsigned short h = bf16rn(x);
  unsigned short l = bf16rn(x - bf16tof(h));
  Bh[(size_t)c * K + k] = h;
  Bl[(size_t)c * K + k] = l;
}

// merged layer weights: Wl[2][128][128] -> Bt [256 cols][128 k]
__global__ void k_conv_wl2(const float* __restrict__ Wl, unsigned short* __restrict__ Bh,
                           unsigned short* __restrict__ Bl) {
  int i = blockIdx.x * blockDim.x + threadIdx.x;
  if (i >= 2 * H * H) return;
  int l = i >> 14;
  int r = i & 16383;
  int k = r >> 7, c = r & 127;
  float x = Wl[i];
  unsigned short h = bf16rn(x);
  unsigned short lo = bf16rn(x - bf16tof(h));
  int col = c + 128 * l;
  Bh[(size_t)col * H + k] = h;
  Bl[(size_t)col * H + k] = lo;
}

// ---------------- split helpers ----------------
__device__ __forceinline__ unsigned int packhi(unsigned int u1, unsigned int u0) {
  return __builtin_amdgcn_perm(u1, u0, 0x07060302u);
}

__device__ __forceinline__ void split8(const float4& a0, const float4& a1, short8v& ah,
                                       short8v& al) {
  float xs[8] = {a0.x, a0.y, a0.z, a0.w, a1.x, a1.y, a1.z, a1.w};
  unsigned int hu[8], lu[8];
#pragma unroll
  for (int j = 0; j < 8; j++) {
    unsigned int u = __float_as_uint(xs[j]);
    hu[j] = u & 0xffff0000u;
    lu[j] = __float_as_uint(xs[j] - __uint_as_float(hu[j]));
  }
  unsigned int hw[4], lw[4];
#pragma unroll
  for (int j = 0; j < 4; j++) {
    hw[j] = packhi(hu[2 * j + 1], hu[2 * j]);
    lw[j] = packhi(lu[2 * j + 1], lu[2 * j]);
  }
  ah = *(short8v*)hw;
  al = *(short8v*)lw;
}

// ---------------- encoder GEMM: 64-row tile, FULL K, direct epilogue ----------------
// 1563 blocks (same granularity as split-K x2's 1564 -> no r12 tail quantization), but no
// partial writes and no k_reduce2 (saves ~255 MB of round-trip traffic + a launch).
// LDS/buffer: A 8 KB + Bh 8 KB + Bl 8 KB = 24 KB; x2 dbuf = 48 KB -> 3 blocks/CU.
__global__ __launch_bounds__(256, 2) void k_gemm_enc(const float* __restrict__ A,
                                                     const unsigned short* __restrict__ Bth,
                                                     const unsigned short* __restrict__ Btl,
                                                     const float* __restrict__ bias,
                                                     float* __restrict__ C, int M, int K,
                                                     int dorelu) {
  __shared__ __align__(16) char smem[2][24576];
  int tid = threadIdx.x;
  int wave = tid >> 6, lane = tid & 63;
  int m0 = blockIdx.x * 64;
  int wn = wave * 32;  // each wave: 64 rows x 32 cols
  int fr = lane & 15, fg = lane >> 4;
  int nIter = K >> 5;  // BK = 32

  f32x4 acc[4][2];
#pragma unroll
  for (int i = 0; i < 4; i++)
#pragma unroll
    for (int j = 0; j < 2; j++) acc[i][j] = (f32x4){0.f, 0.f, 0.f, 0.f};

  int a_row = (lane >> 3);
  int a_s = lane & 7;
  int b_col = (lane >> 2);
  int b_s = lane & 3;

  auto stage = [&](int buf, int k0) {
    char* base = smem[buf];
    // A: 64 rows x 32 fp32 = 8 KB, groups j=0..7 of 8 rows; wave does 2
#pragma unroll
    for (int q = 0; q < 2; q++) {
      int j = wave + 4 * q;
      int row = j * 8 + a_row;
      int grow = m0 + row;
      if (grow >= M) grow = 0;
      GLOAD_LDS16(A + (size_t)grow * K + k0 + ((a_s ^ (row & 7)) << 2), base + j * 1024);
    }
    // Bh/Bl: 128 cols x 32 bf16 = 8 KB each, groups j=0..7 of 16 cols; wave does 2+2
#pragma unroll
    for (int q = 0; q < 2; q++) {
      int j = wave + 4 * q;
      int col = j * 16 + b_col;
      int soff = k0 + ((b_s ^ (col & 3)) << 3);
      GLOAD_LDS16(Bth + (size_t)col * K + soff, base + 8192 + j * 1024);
      GLOAD_LDS16(Btl + (size_t)col * K + soff, base + 16384 + j * 1024);
    }
  };

  stage(0, 0);
  __syncthreads();

  for (int it = 0; it < nIter; ++it) {
    int cur = it & 1;
    if (it + 1 < nIter) stage(cur ^ 1, (it + 1) << 5);
    const char* cb = smem[cur];
    short8v ah[4], al[4];
#pragma unroll
    for (int mf = 0; mf < 4; mf++) {
      int r = 16 * mf + fr;
      int s0 = (2 * fg) ^ (r & 7);
      int s1 = (2 * fg + 1) ^ (r & 7);
      float4 a0 = *(const float4*)(cb + r * 128 + s0 * 16);
      float4 a1 = *(const float4*)(cb + r * 128 + s1 * 16);
      split8(a0, a1, ah[mf], al[mf]);
    }
#pragma unroll
    for (int nf = 0; nf < 2; nf++) {
      int c = wn + 16 * nf + fr;
      int sb = fg ^ (c & 3);
      short8v bh = *(const short8v*)(cb + 8192 + c * 64 + sb * 16);
      short8v bl = *(const short8v*)(cb + 16384 + c * 64 + sb * 16);
#pragma unroll
      for (int mf = 0; mf < 4; mf++) {
        acc[mf][nf] = __builtin_amdgcn_mfma_f32_16x16x32_bf16(ah[mf], bh, acc[mf][nf], 0, 0, 0);
        acc[mf][nf] = __builtin_amdgcn_mfma_f32_16x16x32_bf16(ah[mf], bl, acc[mf][nf], 0, 0, 0);
        acc[mf][nf] = __builtin_amdgcn_mfma_f32_16x16x32_bf16(al[mf], bh, acc[mf][nf], 0, 0, 0);
      }
    }
    __syncthreads();
  }

#pragma unroll
  for (int mf = 0; mf < 4; mf++) {
    int rbase = m0 + 16 * mf + 4 * fg;
#pragma unroll
    for (int nf = 0; nf < 2; nf++) {
      int col = wn + 16 * nf + fr;
      float bv = bias[col];
#pragma unroll
      for (int j = 0; j < 4; j++) {
        int row = rbase + j;
        if (row < M) {
          float v = acc[mf][nf][j] + bv;
          if (dorelu) v = fmaxf(v, 0.f);
          C[(size_t)row * H + col] = v;
        }
      }
    }
  }
}

// ---------------- merged-layer GEMM: GL2[M,256](fp16) (r10 exact: full LDS staging) ---------
__global__ __launch_bounds__(256, 2) void k_gemm_n256(const float* __restrict__ A,
                                                      const unsigned short* __restrict__ Bth,
                                                      const unsigned short* __restrict__ Btl,
                                                      const float* __restrict__ bias,
                                                      __half* __restrict__ C, int M) {
  __shared__ __align__(16) char smem[2][40960];
  const int K = 128;
  int tid = threadIdx.x;
  int wave = tid >> 6, lane = tid & 63;
  int m0 = blockIdx.x * 64;
  int wn = wave * 64;
  int fr = lane & 15, fg = lane >> 4;

  f32x4 acc[4][4];
#pragma unroll
  for (int i = 0; i < 4; i++)
#pragma unroll
    for (int j = 0; j < 4; j++) acc[i][j] = (f32x4){0.f, 0.f, 0.f, 0.f};

  int a_row = (lane >> 3);
  int a_s = lane & 7;
  int b_col = (lane >> 2);
  int b_s = lane & 3;

  auto stage = [&](int buf, int k0) {
    char* base = smem[buf];
#pragma unroll
    for (int q = 0; q < 2; q++) {
      int j = wave + 4 * q;
      int row = j * 8 + a_row;
      int grow = m0 + row;
      if (grow >= M) grow = 0;
      GLOAD_LDS16(A + (size_t)grow * K + k0 + ((a_s ^ (row & 7)) << 2), base + j * 1024);
    }
#pragma unroll
    for (int q = 0; q < 4; q++) {
      int j = wave + 4 * q;
      int col = j * 16 + b_col;
      int soff = k0 + ((b_s ^ (col & 3)) << 3);
      GLOAD_LDS16(Bth + (size_t)col * K + soff, base + 8192 + j * 1024);
      GLOAD_LDS16(Btl + (size_t)col * K + soff, base + 24576 + j * 1024);
    }
  };

  stage(0, 0);
  __syncthreads();

  for (int it = 0; it < 4; ++it) {
    int cur = it & 1;
    if (it + 1 < 4) stage(cur ^ 1, (it + 1) << 5);
    const char* cb = smem[cur];
    short8v ah[4], al[4];
#pragma unroll
    for (int mf = 0; mf < 4; mf++) {
      int r = 16 * mf + fr;
      int s0 = (2 * fg) ^ (r & 7);
      int s1 = (2 * fg + 1) ^ (r & 7);
      float4 a0 = *(const float4*)(cb + r * 128 + s0 * 16);
      float4 a1 = *(const float4*)(cb + r * 128 + s1 * 16);
      split8(a0, a1, ah[mf], al[mf]);
    }
#pragma unroll
    for (int nf = 0; nf < 4; nf++) {
      int c = wn + 16 * nf + fr;
      int sb = fg ^ (c & 3);
      short8v bh = *(const short8v*)(cb + 8192 + c * 64 + sb * 16);
      short8v bl = *(const short8v*)(cb + 24576 + c * 64 + sb * 16);
#pragma unroll
      for (int mf = 0; mf < 4; mf++) {
        acc[mf][nf] = __builtin_amdgcn_mfma_f32_16x16x32_bf16(ah[mf], bh, acc[mf][nf], 0, 0, 0);
        acc[mf][nf] = __builtin_amdgcn_mfma_f32_16x16x32_bf16(ah[mf], bl, acc[mf][nf], 0, 0, 0);
        acc[mf][nf] = __builtin_amdgcn_mfma_f32_16x16x32_bf16(al[mf], bh, acc[mf][nf], 0, 0, 0);
      }
    }
    __syncthreads();
  }

#pragma unroll
  for (int mf = 0; mf < 4; mf++) {
    int rbase = m0 + 16 * mf + 4 * fg;
#pragma unroll
    for (int nf = 0; nf < 4; nf++) {
      int col = wn + 16 * nf + fr;
      float bv = bias[col];
#pragma unroll
      for (int j = 0; j < 4; j++) {
        int row = rbase + j;
        if (row < M) C[(size_t)row * 256 + col] = __float2half(acc[mf][nf][j] + bv);
      }
    }
  }
}

// ---------------- company encoder (K=27) ----------------
__global__ void k_enc_comp(const float* __restrict__ X, const float* __restrict__ Wc,
                           const float* __restrict__ bc, float* __restrict__ hc) {
  int tid = threadIdx.x;
  int r = blockIdx.x * 2 + (tid >> 7);
  int j = tid & 127;
  if (r >= NCOMP) return;
  float acc = bc[j];
  const float* x = X + (size_t)r * DC;
#pragma unroll
  for (int k = 0; k < DC; k++) acc = fmaf(x[k], Wc[k * H + j], acc);
  hc[(size_t)r * H + j] = fmaxf(acc, 0.f);
}

// ---------------- fused per-node GAT layer (r10 loop; EF CSR-ordered, no eid) ----------
__global__ __launch_bounds__(128) void k_node(
    const __half* __restrict__ gl, const float* __restrict__ ef, const int* __restrict__ srcs,
    const int* __restrict__ csr_off,
    const float* __restrict__ Wr, const float* __restrict__ br, const float* __restrict__ We,
    const float* __restrict__ be, const float* __restrict__ att,
    const float* __restrict__ bias_out, const float* __restrict__ lng,
    const float* __restrict__ lnb, float* __restrict__ hc) {
  int v = blockIdx.x;
  int t = threadIdx.x;
  __shared__ float hcs[H];
  __shared__ float red[2], redq[2];
  float x = hc[(size_t)v * H + t];
  hcs[t] = x;
  float wre[EDIM];
#pragma unroll
  for (int k = 0; k < EDIM; k++) wre[k] = We[k * H + t];
  float attv = att[t];
  float bev = be[t];
  __syncthreads();
  float grv = br[t];
  for (int k = 0; k < H; k++) grv = fmaf(hcs[k], Wr[k * H + t], grv);
  float grb = grv + bev;

  int e0 = csr_off[v], e1 = csr_off[v + 1];
  float m = -INFINITY, s = 0.f, acc = 0.f;
  int i = e0;
  int sid = 0;
  if (i < e1) sid = srcs[i];
  while (i < e1) {
    float glv = __half2float(gl[(size_t)sid * 256 + t]);
    const float* efr = ef + (size_t)i * EDIMP;  // CSR-ordered: sequential stream
    float4 f0 = *(const float4*)(efr);
    float4 f1 = *(const float4*)(efr + 4);
    float2 f2 = *(const float2*)(efr + 8);
    int ni = i + 1;
    if (ni < e1) sid = srcs[ni];  // prefetch next src index
    float ge = grb;
    ge = fmaf(f0.x, wre[0], ge);
    ge = fmaf(f0.y, wre[1], ge);
    ge = fmaf(f0.z, wre[2], ge);
    ge = fmaf(f0.w, wre[3], ge);
    ge = fmaf(f1.x, wre[4], ge);
    ge = fmaf(f1.y, wre[5], ge);
    ge = fmaf(f1.z, wre[6], ge);
    ge = fmaf(f1.w, wre[7], ge);
    ge = fmaf(f2.x, wre[8], ge);
    ge = fmaf(f2.y, wre[9], ge);
    float ev = glv + ge;
    ev = ev > 0.f ? ev : 0.2f * ev;
    float logit = group32_sum(ev * attv);
    if (logit > m) {  // rare: rescale to new max (exp(-inf)=0 on first edge)
      float scale = __expf(m - logit);
      s = s * scale + 1.f;
      acc = acc * scale + glv;
      m = logit;
    } else {  // common path
      float z = __expf(logit - m);
      s += z;
      acc = fmaf(z, glv, acc);
    }
    i = ni;
  }
  float outv = acc / (s + 1e-16f);
  outv += bias_out[t];
  outv = fmaxf(outv, 0.f);
  float y = x + outv;
  float sv = y, qv = y * y;
#pragma unroll
  for (int mm = 32; mm > 0; mm >>= 1) {
    sv += __shfl_xor(sv, mm);
    qv += __shfl_xor(qv, mm);
  }
  int wid = t >> 6, lane = t & 63;
  if (lane == 0) {
    red[wid] = sv;
    redq[wid] = qv;
  }
  __syncthreads();
  float mean = (red[0] + red[1]) * (1.f / H);
  float var = (redq[0] + redq[1]) * (1.f / H) - mean * mean;
  float r = rsqrtf(var + 1e-5f);
  hc[(size_t)v * H + t] = (y - mean) * r * lng[t] + lnb[t];
}

// ---------------- segment mean (sorted segments) ----------------
template <int CHUNK>
__global__ __launch_bounds__(128) void k_segmean(const float* __restrict__ X,
                                                 const int* __restrict__ seg, int n,
                                                 float* __restrict__ sum, int* __restrict__ cnt) {
  int t = threadIdx.x;
  int n0 = blockIdx.x * CHUNK;
  int n1 = min(n0 + CHUNK, n);
  float acc = 0.f;
  int c = 0;
  int curs = -1;
  for (int i = n0; i < n1; ++i) {
    int sg = seg[i];
    if (sg != curs) {
      if (curs >= 0) {
        atomicAdd(&sum[(size_t)curs * H + t], acc);
        if (t == 0) atomicAdd(&cnt[curs], c);
      }
      curs = sg;
      acc = 0.f;
      c = 0;
    }
    acc += X[(size_t)i * H + t];
    c++;
  }
  if (curs >= 0) {
    atomicAdd(&sum[(size_t)curs * H + t], acc);
    if (t == 0) atomicAdd(&cnt[curs], c);
  }
}

// ---------------- gated readout + MLP ----------------
__global__ __launch_bounds__(128) void k_readout(const float* __restrict__ pf,
                                                 const float* __restrict__ pc,
                                                 const int* __restrict__ cf,
                                                 const int* __restrict__ cc,
                                                 const float* __restrict__ Wg,
                                                 const float* __restrict__ bg,
                                                 const float* __restrict__ W1,
                                                 const float* __restrict__ b1,
                                                 const float* __restrict__ W2,
                                                 const float* __restrict__ b2,
                                                 float* __restrict__ out) {
  int b = blockIdx.x, t = threadIdx.x;
  __shared__ float hs[H];
  __shared__ float red[2], red2[2];
  int wid = t >> 6, lane = t & 63;
  float nf = fmaxf((float)cf[b], 1.f);
  float nc = fmaxf((float)cc[b], 1.f);
  float pfv = pf[(size_t)b * H + t] / nf;
  float pcv = pc[(size_t)b * H + t] / nc;
  float gp = pfv * Wg[t] + pcv * Wg[H + t];
  float sv = gp;
#pragma unroll
  for (int mm = 32; mm > 0; mm >>= 1) sv += __shfl_xor(sv, mm);
  if (lane == 0) red[wid] = sv;
  __syncthreads();
  float g = 1.f / (1.f + expf(-(red[0] + red[1] + bg[0])));
  float h = g * pfv + (1.f - g) * pcv;
  hs[t] = h;
  __syncthreads();
  float a = b1[t];
  for (int k = 0; k < H; k++) a = fmaf(hs[k], W1[k * H + t], a);
  a = fmaxf(a, 0.f);
  float p = a * W2[t];
#pragma unroll
  for (int mm = 32; mm > 0; mm >>= 1) p += __shfl_xor(p, mm);
  if (lane == 0) red2[wid] = p;
  __syncthreads();
  if (t == 0) out[b] = red2[0] + red2[1] + b2[0];
}

extern "C" void kernel_launch(void* const* d_in, const int* in_sizes, int n_in, void* d_out,
                              int out_size, void* d_ws, size_t ws_size, hipStream_t stream) {
  const float* x_fact = (const float*)d_in[0];
  const float* x_comp = (const float*)d_in[1];
  const float* ea = (const float*)d_in[2];
  const int* eidx = (const int*)d_in[3];
  const int* batf = (const int*)d_in[4];
  const int* batc = (const int*)d_in[5];
  const float* lam = (const float*)d_in[6];
  const float* Wf = (const float*)d_in[7];
  const float* bf = (const float*)d_in[8];
  const float* Wc = (const float*)d_in[9];
  const float* bc = (const float*)d_in[10];
  const float* Wl = (const float*)d_in[11];
  const float* bl = (const float*)d_in[12];
  const float* Wr = (const float*)d_in[13];
  const float* br_ = (const float*)d_in[14];
  const float* We = (const float*)d_in[15];
  const float* be = (const float*)d_in[16];
  const float* att = (const float*)d_in[17];
  const float* b_out = (const float*)d_in[18];
  const float* lng = (const float*)d_in[19];
  const float* lnb = (const float*)d_in[20];
  const float* Wg = (const float*)d_in[21];
  const float* bg = (const float*)d_in[22];
  const float* W1 = (const float*)d_in[23];
  const float* b1 = (const float*)d_in[24];
  const float* W2 = (const float*)d_in[25];
  const float* b2 = (const float*)d_in[26];
  float* out = (float*)d_out;

  char* w = (char*)d_ws;
  auto carve = [&](size_t bytes) -> char* {
    char* p = w;
    w += (bytes + 255) & ~(size_t)255;
    return p;
  };
  float* HF = (float*)carve((size_t)NFAC * H * 4);
  __half* GL2 = (__half*)carve((size_t)NFAC * 256 * 2);  // [NFAC][256] fp16
  float* HC = (float*)carve((size_t)NCOMP * H * 4);
  float* EF = (float*)carve((size_t)NEDGE * EDIMP * 4);
  int* OFF = (int*)carve(4100 * 4);
  int* POS = (int*)carve((size_t)NEDGE * 4);
  int* SRCS = (int*)carve((size_t)NEDGE * 4);
  unsigned short* WfH = (unsigned short*)carve((size_t)DF * H * 2);
  unsigned short* WfL = (unsigned short*)carve((size_t)DF * H * 2);
  unsigned short* WlH2 = (unsigned short*)carve((size_t)256 * H * 2);
  unsigned short* WlL2 = (unsigned short*)carve((size_t)256 * H * 2);
  char* zbase = w;
  int* DEG = (int*)carve(4096 * 4);
  int* CUR = (int*)carve(4096 * 4);
  float* PF = (float*)carve((size_t)NB * H * 4);
  float* PC = (float*)carve((size_t)NB * H * 4);
  int* CF = (int*)carve(NB * 4);
  int* CC = (int*)carve(NB * 4);
  size_t zbytes = (size_t)(w - zbase);
  hipMemsetAsync(zbase, 0, zbytes, stream);

  const int* srcArr = eidx;
  const int* dstArr = eidx + NEDGE;

  k_hist<<<(NEDGE + 255) / 256, 256, 0, stream>>>(dstArr, DEG);
  k_scan<<<1, 1024, 0, stream>>>(DEG, OFF);
  k_scatter<<<(NEDGE + 255) / 256, 256, 0, stream>>>(dstArr, srcArr, OFF, CUR, POS, SRCS);
  k_edge_feat<<<(NEDGE + 255) / 256, 256, 0, stream>>>(ea, lam, POS, EF);

  // weight preconvert
  k_conv_w<<<(DF * H + 255) / 256, 256, 0, stream>>>(Wf, WfH, WfL, DF);
  k_conv_wl2<<<(2 * H * H + 255) / 256, 256, 0, stream>>>(Wl, WlH2, WlL2);

  // encoder GEMM: 64-row tiles, full K, direct bias+relu epilogue (no split-K, no reduce2)
  k_gemm_enc<<<(NFAC + 63) / 64, 256, 0, stream>>>(x_fact, WfH, WfL, bf, HF, NFAC, DF, 1);
  k_enc_comp<<<NCOMP / 2, 256, 0, stream>>>(x_comp, Wc, bc, HC);

  // merged GL GEMM -> fp16 GL2
  k_gemm_n256<<<(NFAC + 63) / 64, 256, 0, stream>>>(HF, WlH2, WlL2, bl, GL2, NFAC);

  for (int l = 0; l < 2; l++) {
    k_node<<<NCOMP, 128, 0, stream>>>(GL2 + l * 128, EF, SRCS, OFF,
                                      Wr + (size_t)l * H * H, br_ + l * H,
                                      We + (size_t)l * EDIM * H, be + l * H, att + l * H,
                                      b_out + l * H, lng + l * H, lnb + l * H, HC);
  }

  k_segmean<128><<<(NFAC + 127) / 128, 128, 0, stream>>>(HF, batf, NFAC, PF, CF);
  k_segmean<64><<<(NCOMP + 63) / 64, 128, 0, stream>>>(HC, batc, NCOMP, PC, CC);
  k_readout<<<NB, 128, 0, stream>>>(PF, PC, CF, CC, Wg, bg, W1, b1, W2, b2, out);
}

// Round 16
// 686.824 us; speedup vs baseline: 1.0181x; 1.0181x over previous
//
#include <hip/hip_runtime.h>
#include <hip/hip_bf16.h>
#include <hip/hip_fp16.h>
#include <math.h>

#define NFAC 100000
#define NCOMP 4000
#define NEDGE 500000
#define NB 256
#define DF 1536
#define DC 27
#define H 128
#define EDIM 10
#define EDIMP 16  // padded EF row (64B, aligned vector loads)

typedef __attribute__((ext_vector_type(8))) short short8v;
typedef __attribute__((ext_vector_type(4))) float f32x4;

#define GLOAD_LDS16(g, l)                                                              \
  __builtin_amdgcn_global_load_lds((const __attribute__((address_space(1))) unsigned int*)(g), \
                                   (__attribute__((address_space(3))) unsigned int*)(l), 16, 0, 0)

__device__ __forceinline__ float group32_sum(float v) {
#pragma unroll
  for (int m = 16; m > 0; m >>= 1) v += __shfl_xor(v, m);
  return v;
}

__device__ __forceinline__ unsigned short bf16rn(float x) {
  unsigned int u = __float_as_uint(x);
  unsigned int r = (u + 0x7fffu + ((u >> 16) & 1u)) >> 16;
  return (unsigned short)r;
}
__device__ __forceinline__ float bf16tof(unsigned short h) {
  return __uint_as_float(((unsigned int)h) << 16);
}

// ---------------- edge features, written in CSR order (POS[e] from k_scatter) ----------------
__global__ void k_edge_feat(const float* __restrict__ ea, const float* __restrict__ lamp,
                            const int* __restrict__ pos, float* __restrict__ ef) {
  int e = blockIdx.x * blockDim.x + threadIdx.x;
  if (e >= NEDGE) return;
  float s   = fminf(fmaxf(ea[2 * e], -1.f), 1.f);
  float dec = fminf(fmaxf(ea[2 * e + 1], 0.f), 1.f);
  float lam = fmaxf(lamp[0], 1e-6f);
  float dt  = -logf(fmaxf(dec, 1e-6f)) / lam;
  float t   = log1pf(fmaxf(dt, 0.f)) * (1.f / 30.f);
  float* o = ef + (size_t)pos[e] * EDIMP;
  o[0] = s;
  o[1] = dec;
#pragma unroll
  for (int k = 1; k < 8; k++) o[1 + k] = __sinf(t * (float)k);
  o[9] = t;
  o[10] = 0.f; o[11] = 0.f; o[12] = 0.f; o[13] = 0.f; o[14] = 0.f; o[15] = 0.f;
}

// ---------------- CSR build ----------------
__global__ void k_hist(const int* __restrict__ dst, int* __restrict__ deg) {
  int e = blockIdx.x * blockDim.x + threadIdx.x;
  if (e < NEDGE) atomicAdd(&deg[dst[e]], 1);
}

__global__ __launch_bounds__(1024) void k_scan(const int* __restrict__ deg, int* __restrict__ off) {
  __shared__ int s[4096];
  int t = threadIdx.x;
  for (int i = t; i < 4096; i += 1024) s[i] = (i < NCOMP) ? deg[i] : 0;
  __syncthreads();
  for (int d = 1; d < 4096; d <<= 1) {
    int vals[4];
#pragma unroll
    for (int j = 0; j < 4; j++) {
      int i = t + j * 1024;
      vals[j] = (i >= d) ? s[i - d] : 0;
    }
    __syncthreads();
#pragma unroll
    for (int j = 0; j < 4; j++) {
      int i = t + j * 1024;
      s[i] += vals[j];
    }
    __syncthreads();
  }
  for (int i = t; i < 4096; i += 1024) off[i + 1] = s[i];
  if (t == 0) off[0] = 0;
}

// scatter: build srcs[] in CSR order and record POS[e] for edge-feature placement
__global__ void k_scatter(const int* __restrict__ dst, const int* __restrict__ src,
                          const int* __restrict__ off, int* __restrict__ cur,
                          int* __restrict__ pos, int* __restrict__ srcs) {
  int e = blockIdx.x * blockDim.x + threadIdx.x;
  if (e < NEDGE) {
    int d = dst[e];
    int p = atomicAdd(&cur[d], 1);
    int slot = off[d] + p;
    pos[e] = slot;
    srcs[slot] = src[e];
  }
}

// ---------------- weight preconvert: W[K][128] fp32 -> Bt_hi/Bt_lo [128][K] bf16 ----------------
__global__ void k_conv_w(const float* __restrict__ W, unsigned short* __restrict__ Bh,
                         unsigned short* __restrict__ Bl, int K) {
  int i = blockIdx.x * blockDim.x + threadIdx.x;
  if (i >= K * H) return;
  int k = i >> 7, c = i & 127;
  float x = W[i];
  unsigned short h = bf16rn(x);
  unsigned short l = bf16rn(x - bf16tof(h));
  Bh[(size_t)c * K + k] = h;
  Bl[(size_t)c * K + k] = l;
}

// merged layer weights: Wl[2][128][128] -> Bt [256 cols][128 k]
__global__ void k_conv_wl2(const float* __restrict__ Wl, unsigned short* __restrict__ Bh,
                           unsigned short* __restrict__ Bl) {
  int i = blockIdx.x * blockDim.x + threadIdx.x;
  if (i >= 2 * H * H) return;
  int l = i >> 14;
  int r = i & 16383;
  int k = r >> 7, c = r & 127;
  float x = Wl[i];
  unsigned short h = bf16rn(x);
  unsigned short lo = bf16rn(x - bf16tof(h));
  int col = c + 128 * l;
  Bh[(size_t)col * H + k] = h;
  Bl[(size_t)col * H + k] = lo;
}

// ---------------- split helpers ----------------
__device__ __forceinline__ unsigned int packhi(unsigned int u1, unsigned int u0) {
  return __builtin_amdgcn_perm(u1, u0, 0x07060302u);
}

__device__ __forceinline__ void split8(const float4& a0, const float4& a1, short8v& ah,
                                       short8v& al) {
  float xs[8] = {a0.x, a0.y, a0.z, a0.w, a1.x, a1.y, a1.z, a1.w};
  unsigned int hu[8], lu[8];
#pragma unroll
  for (int j = 0; j < 8; j++) {
    unsigned int u = __float_as_uint(xs[j]);
    hu[j] = u & 0xffff0000u;
    lu[j] = __float_as_uint(xs[j] - __uint_as_float(hu[j]));
  }
  unsigned int hw[4], lw[4];
#pragma unroll
  for (int j = 0; j < 4; j++) {
    hw[j] = packhi(hu[2 * j + 1], hu[2 * j]);
    lw[j] = packhi(lu[2 * j + 1], lu[2 * j]);
  }
  ah = *(short8v*)hw;
  al = *(short8v*)lw;
}

// ---------------- encoder GEMM (r10/r14 exact): full LDS staging, split-K ----------------
__global__ __launch_bounds__(256, 2) void k_gemm_mfma(const float* __restrict__ A,
                                                      const unsigned short* __restrict__ Bth,
                                                      const unsigned short* __restrict__ Btl,
                                                      const float* __restrict__ bias,
                                                      float* __restrict__ C, int M, int K,
                                                      int dorelu, float* __restrict__ Cpart) {
  __shared__ __align__(16) char smem[2][32768];
  int tid = threadIdx.x;
  int wave = tid >> 6, lane = tid & 63;
  int m0 = blockIdx.x * 128;
  int wm = (wave >> 1) * 64, wn = (wave & 1) * 64;
  int fr = lane & 15, fg = lane >> 4;
  int nsplit = gridDim.y;
  int Ks = K / nsplit;
  int kbeg = blockIdx.y * Ks;
  int nIter = Ks >> 5;

  f32x4 acc[4][4];
#pragma unroll
  for (int i = 0; i < 4; i++)
#pragma unroll
    for (int j = 0; j < 4; j++) acc[i][j] = (f32x4){0.f, 0.f, 0.f, 0.f};

  int a_row = (lane >> 3);
  int a_s = lane & 7;
  int b_col = (lane >> 2);
  int b_s = lane & 3;

  auto stage = [&](int buf, int k0) {
    char* base = smem[buf];
#pragma unroll
    for (int q = 0; q < 4; q++) {
      int j = wave + 4 * q;
      int row = j * 8 + a_row;
      int grow = m0 + row;
      if (grow >= M) grow = 0;
      const float* src = A + (size_t)grow * K + k0 + ((a_s ^ (row & 7)) << 2);
      GLOAD_LDS16(src, base + j * 1024);
    }
#pragma unroll
    for (int q = 0; q < 2; q++) {
      int j = wave + 4 * q;
      int col = j * 16 + b_col;
      int soff = k0 + ((b_s ^ (col & 3)) << 3);
      GLOAD_LDS16(Bth + (size_t)col * K + soff, base + 16384 + j * 1024);
      GLOAD_LDS16(Btl + (size_t)col * K + soff, base + 24576 + j * 1024);
    }
  };

  stage(0, kbeg);
  __syncthreads();

  for (int it = 0; it < nIter; ++it) {
    int cur = it & 1;
    if (it + 1 < nIter) stage(cur ^ 1, kbeg + ((it + 1) << 5));
    const char* cb = smem[cur];
    short8v ah[4], al[4];
#pragma unroll
    for (int mf = 0; mf < 4; mf++) {
      int r = wm + 16 * mf + fr;
      int s0 = (2 * fg) ^ (r & 7);
      int s1 = (2 * fg + 1) ^ (r & 7);
      float4 a0 = *(const float4*)(cb + r * 128 + s0 * 16);
      float4 a1 = *(const float4*)(cb + r * 128 + s1 * 16);
      split8(a0, a1, ah[mf], al[mf]);
    }
#pragma unroll
    for (int nf = 0; nf < 4; nf++) {
      int c = wn + 16 * nf + fr;
      int sb = fg ^ (c & 3);
      short8v bh = *(const short8v*)(cb + 16384 + c * 64 + sb * 16);
      short8v bl = *(const short8v*)(cb + 24576 + c * 64 + sb * 16);
#pragma unroll
      for (int mf = 0; mf < 4; mf++) {
        acc[mf][nf] = __builtin_amdgcn_mfma_f32_16x16x32_bf16(ah[mf], bh, acc[mf][nf], 0, 0, 0);
        acc[mf][nf] = __builtin_amdgcn_mfma_f32_16x16x32_bf16(ah[mf], bl, acc[mf][nf], 0, 0, 0);
        acc[mf][nf] = __builtin_amdgcn_mfma_f32_16x16x32_bf16(al[mf], bh, acc[mf][nf], 0, 0, 0);
      }
    }
    __syncthreads();
  }

  if (nsplit == 1) {
#pragma unroll
    for (int mf = 0; mf < 4; mf++) {
      int rbase = m0 + wm + 16 * mf + 4 * fg;
#pragma unroll
      for (int nf = 0; nf < 4; nf++) {
        int col = wn + 16 * nf + fr;
        float bv = bias[col];
#pragma unroll
        for (int j = 0; j < 4; j++) {
          int row = rbase + j;
          if (row < M) {
            float v = acc[mf][nf][j] + bv;
            if (dorelu) v = fmaxf(v, 0.f);
            C[(size_t)row * H + col] = v;
          }
        }
      }
    }
  } else {
    float* P = Cpart + (size_t)blockIdx.y * M * H;
#pragma unroll
    for (int mf = 0; mf < 4; mf++) {
      int rbase = m0 + wm + 16 * mf + 4 * fg;
#pragma unroll
      for (int nf = 0; nf < 4; nf++) {
        int col = wn + 16 * nf + fr;
#pragma unroll
        for (int j = 0; j < 4; j++) {
          int row = rbase + j;
          if (row < M) P[(size_t)row * H + col] = acc[mf][nf][j];
        }
      }
    }
  }
}

// ---------------- split-K reduce: C = relu(P0 + P1 + bias) ----------------
__global__ __launch_bounds__(256) void k_reduce2(const float* __restrict__ P0,
                                                 const float* __restrict__ P1,
                                                 const float* __restrict__ bias,
                                                 float* __restrict__ C, int total4) {
  int i = blockIdx.x * blockDim.x + threadIdx.x;
  if (i >= total4) return;
  float4 a = ((const float4*)P0)[i];
  float4 b = ((const float4*)P1)[i];
  float4 bv = ((const float4*)bias)[i & 31];
  float4 r;
  r.x = fmaxf(a.x + b.x + bv.x, 0.f);
  r.y = fmaxf(a.y + b.y + bv.y, 0.f);
  r.z = fmaxf(a.z + b.z + bv.z, 0.f);
  r.w = fmaxf(a.w + b.w + bv.w, 0.f);
  ((float4*)C)[i] = r;
}

// ---------------- merged-layer GEMM: GL2[M,256](fp16) (r10 exact: full LDS staging) ---------
__global__ __launch_bounds__(256, 2) void k_gemm_n256(const float* __restrict__ A,
                                                      const unsigned short* __restrict__ Bth,
                                                      const unsigned short* __restrict__ Btl,
                                                      const float* __restrict__ bias,
                                                      __half* __restrict__ C, int M) {
  __shared__ __align__(16) char smem[2][40960];
  const int K = 128;
  int tid = threadIdx.x;
  int wave = tid >> 6, lane = tid & 63;
  int m0 = blockIdx.x * 64;
  int wn = wave * 64;
  int fr = lane & 15, fg = lane >> 4;

  f32x4 acc[4][4];
#pragma unroll
  for (int i = 0; i < 4; i++)
#pragma unroll
    for (int j = 0; j < 4; j++) acc[i][j] = (f32x4){0.f, 0.f, 0.f, 0.f};

  int a_row = (lane >> 3);
  int a_s = lane & 7;
  int b_col = (lane >> 2);
  int b_s = lane & 3;

  auto stage = [&](int buf, int k0) {
    char* base = smem[buf];
#pragma unroll
    for (int q = 0; q < 2; q++) {
      int j = wave + 4 * q;
      int row = j * 8 + a_row;
      int grow = m0 + row;
      if (grow >= M) grow = 0;
      GLOAD_LDS16(A + (size_t)grow * K + k0 + ((a_s ^ (row & 7)) << 2), base + j * 1024);
    }
#pragma unroll
    for (int q = 0; q < 4; q++) {
      int j = wave + 4 * q;
      int col = j * 16 + b_col;
      int soff = k0 + ((b_s ^ (col & 3)) << 3);
      GLOAD_LDS16(Bth + (size_t)col * K + soff, base + 8192 + j * 1024);
      GLOAD_LDS16(Btl + (size_t)col * K + soff, base + 24576 + j * 1024);
    }
  };

  stage(0, 0);
  __syncthreads();

  for (int it = 0; it < 4; ++it) {
    int cur = it & 1;
    if (it + 1 < 4) stage(cur ^ 1, (it + 1) << 5);
    const char* cb = smem[cur];
    short8v ah[4], al[4];
#pragma unroll
    for (int mf = 0; mf < 4; mf++) {
      int r = 16 * mf + fr;
      int s0 = (2 * fg) ^ (r & 7);
      int s1 = (2 * fg + 1) ^ (r & 7);
      float4 a0 = *(const float4*)(cb + r * 128 + s0 * 16);
      float4 a1 = *(const float4*)(cb + r * 128 + s1 * 16);
      split8(a0, a1, ah[mf], al[mf]);
    }
#pragma unroll
    for (int nf = 0; nf < 4; nf++) {
      int c = wn + 16 * nf + fr;
      int sb = fg ^ (c & 3);
      short8v bh = *(const short8v*)(cb + 8192 + c * 64 + sb * 16);
      short8v bl = *(const short8v*)(cb + 24576 + c * 64 + sb * 16);
#pragma unroll
      for (int mf = 0; mf < 4; mf++) {
        acc[mf][nf] = __builtin_amdgcn_mfma_f32_16x16x32_bf16(ah[mf], bh, acc[mf][nf], 0, 0, 0);
        acc[mf][nf] = __builtin_amdgcn_mfma_f32_16x16x32_bf16(ah[mf], bl, acc[mf][nf], 0, 0, 0);
        acc[mf][nf] = __builtin_amdgcn_mfma_f32_16x16x32_bf16(al[mf], bh, acc[mf][nf], 0, 0, 0);
      }
    }
    __syncthreads();
  }

#pragma unroll
  for (int mf = 0; mf < 4; mf++) {
    int rbase = m0 + 16 * mf + 4 * fg;
#pragma unroll
    for (int nf = 0; nf < 4; nf++) {
      int col = wn + 16 * nf + fr;
      float bv = bias[col];
#pragma unroll
      for (int j = 0; j < 4; j++) {
        int row = rbase + j;
        if (row < M) C[(size_t)row * 256 + col] = __float2half(acc[mf][nf][j] + bv);
      }
    }
  }
}

// ---------------- company encoder (K=27) ----------------
__global__ void k_enc_comp(const float* __restrict__ X, const float* __restrict__ Wc,
                           const float* __restrict__ bc, float* __restrict__ hc) {
  int tid = threadIdx.x;
  int r = blockIdx.x * 2 + (tid >> 7);
  int j = tid & 127;
  if (r >= NCOMP) return;
  float acc = bc[j];
  const float* x = X + (size_t)r * DC;
#pragma unroll
  for (int k = 0; k < DC; k++) acc = fmaf(x[k], Wc[k * H + j], acc);
  hc[(size_t)r * H + j] = fmaxf(acc, 0.f);
}

// ---------------- fused per-node GAT layer (r10 loop; EF CSR-ordered, no eid) ----------
__global__ __launch_bounds__(128) void k_node(
    const __half* __restrict__ gl, const float* __restrict__ ef, const int* __restrict__ srcs,
    const int* __restrict__ csr_off,
    const float* __restrict__ Wr, const float* __restrict__ br, const float* __restrict__ We,
    const float* __restrict__ be, const float* __restrict__ att,
    const float* __restrict__ bias_out, const float* __restrict__ lng,
    const float* __restrict__ lnb, float* __restrict__ hc) {
  int v = blockIdx.x;
  int t = threadIdx.x;
  __shared__ float hcs[H];
  __shared__ float red[2], redq[2];
  float x = hc[(size_t)v * H + t];
  hcs[t] = x;
  float wre[EDIM];
#pragma unroll
  for (int k = 0; k < EDIM; k++) wre[k] = We[k * H + t];
  float attv = att[t];
  float bev = be[t];
  __syncthreads();
  float grv = br[t];
  for (int k = 0; k < H; k++) grv = fmaf(hcs[k], Wr[k * H + t], grv);
  float grb = grv + bev;

  int e0 = csr_off[v], e1 = csr_off[v + 1];
  float m = -INFINITY, s = 0.f, acc = 0.f;
  int i = e0;
  int sid = 0;
  if (i < e1) sid = srcs[i];
  while (i < e1) {
    float glv = __half2float(gl[(size_t)sid * 256 + t]);
    const float* efr = ef + (size_t)i * EDIMP;  // CSR-ordered: sequential stream
    float4 f0 = *(const float4*)(efr);
    float4 f1 = *(const float4*)(efr + 4);
    float2 f2 = *(const float2*)(efr + 8);
    int ni = i + 1;
    if (ni < e1) sid = srcs[ni];  // prefetch next src index
    float ge = grb;
    ge = fmaf(f0.x, wre[0], ge);
    ge = fmaf(f0.y, wre[1], ge);
    ge = fmaf(f0.z, wre[2], ge);
    ge = fmaf(f0.w, wre[3], ge);
    ge = fmaf(f1.x, wre[4], ge);
    ge = fmaf(f1.y, wre[5], ge);
    ge = fmaf(f1.z, wre[6], ge);
    ge = fmaf(f1.w, wre[7], ge);
    ge = fmaf(f2.x, wre[8], ge);
    ge = fmaf(f2.y, wre[9], ge);
    float ev = glv + ge;
    ev = ev > 0.f ? ev : 0.2f * ev;
    float logit = group32_sum(ev * attv);
    if (logit > m) {  // rare: rescale to new max (exp(-inf)=0 on first edge)
      float scale = __expf(m - logit);
      s = s * scale + 1.f;
      acc = acc * scale + glv;
      m = logit;
    } else {  // common path
      float z = __expf(logit - m);
      s += z;
      acc = fmaf(z, glv, acc);
    }
    i = ni;
  }
  float outv = acc / (s + 1e-16f);
  outv += bias_out[t];
  outv = fmaxf(outv, 0.f);
  float y = x + outv;
  float sv = y, qv = y * y;
#pragma unroll
  for (int mm = 32; mm > 0; mm >>= 1) {
    sv += __shfl_xor(sv, mm);
    qv += __shfl_xor(qv, mm);
  }
  int wid = t >> 6, lane = t & 63;
  if (lane == 0) {
    red[wid] = sv;
    redq[wid] = qv;
  }
  __syncthreads();
  float mean = (red[0] + red[1]) * (1.f / H);
  float var = (redq[0] + redq[1]) * (1.f / H) - mean * mean;
  float r = rsqrtf(var + 1e-5f);
  hc[(size_t)v * H + t] = (y - mean) * r * lng[t] + lnb[t];
}

// ---------------- segment mean (sorted segments) ----------------
template <int CHUNK>
__global__ __launch_bounds__(128) void k_segmean(const float* __restrict__ X,
                                                 const int* __restrict__ seg, int n,
                                                 float* __restrict__ sum, int* __restrict__ cnt) {
  int t = threadIdx.x;
  int n0 = blockIdx.x * CHUNK;
  int n1 = min(n0 + CHUNK, n);
  float acc = 0.f;
  int c = 0;
  int curs = -1;
  for (int i = n0; i < n1; ++i) {
    int sg = seg[i];
    if (sg != curs) {
      if (curs >= 0) {
        atomicAdd(&sum[(size_t)curs * H + t], acc);
        if (t == 0) atomicAdd(&cnt[curs], c);
      }
      curs = sg;
      acc = 0.f;
      c = 0;
    }
    acc += X[(size_t)i * H + t];
    c++;
  }
  if (curs >= 0) {
    atomicAdd(&sum[(size_t)curs * H + t], acc);
    if (t == 0) atomicAdd(&cnt[curs], c);
  }
}

// ---------------- gated readout + MLP ----------------
__global__ __launch_bounds__(128) void k_readout(const float* __restrict__ pf,
                                                 const float* __restrict__ pc,
                                                 const int* __restrict__ cf,
                                                 const int* __restrict__ cc,
                                                 const float* __restrict__ Wg,
                                                 const float* __restrict__ bg,
                                                 const float* __restrict__ W1,
                                                 const float* __restrict__ b1,
                                                 const float* __restrict__ W2,
                                                 const float* __restrict__ b2,
                                                 float* __restrict__ out) {
  int b = blockIdx.x, t = threadIdx.x;
  __shared__ float hs[H];
  __shared__ float red[2], red2[2];
  int wid = t >> 6, lane = t & 63;
  float nf = fmaxf((float)cf[b], 1.f);
  float nc = fmaxf((float)cc[b], 1.f);
  float pfv = pf[(size_t)b * H + t] / nf;
  float pcv = pc[(size_t)b * H + t] / nc;
  float gp = pfv * Wg[t] + pcv * Wg[H + t];
  float sv = gp;
#pragma unroll
  for (int mm = 32; mm > 0; mm >>= 1) sv += __shfl_xor(sv, mm);
  if (lane == 0) red[wid] = sv;
  __syncthreads();
  float g = 1.f / (1.f + expf(-(red[0] + red[1] + bg[0])));
  float h = g * pfv + (1.f - g) * pcv;
  hs[t] = h;
  __syncthreads();
  float a = b1[t];
  for (int k = 0; k < H; k++) a = fmaf(hs[k], W1[k * H + t], a);
  a = fmaxf(a, 0.f);
  float p = a * W2[t];
#pragma unroll
  for (int mm = 32; mm > 0; mm >>= 1) p += __shfl_xor(p, mm);
  if (lane == 0) red2[wid] = p;
  __syncthreads();
  if (t == 0) out[b] = red2[0] + red2[1] + b2[0];
}

extern "C" void kernel_launch(void* const* d_in, const int* in_sizes, int n_in, void* d_out,
                              int out_size, void* d_ws, size_t ws_size, hipStream_t stream) {
  const float* x_fact = (const float*)d_in[0];
  const float* x_comp = (const float*)d_in[1];
  const float* ea = (const float*)d_in[2];
  const int* eidx = (const int*)d_in[3];
  const int* batf = (const int*)d_in[4];
  const int* batc = (const int*)d_in[5];
  const float* lam = (const float*)d_in[6];
  const float* Wf = (const float*)d_in[7];
  const float* bf = (const float*)d_in[8];
  const float* Wc = (const float*)d_in[9];
  const float* bc = (const float*)d_in[10];
  const float* Wl = (const float*)d_in[11];
  const float* bl = (const float*)d_in[12];
  const float* Wr = (const float*)d_in[13];
  const float* br_ = (const float*)d_in[14];
  const float* We = (const float*)d_in[15];
  const float* be = (const float*)d_in[16];
  const float* att = (const float*)d_in[17];
  const float* b_out = (const float*)d_in[18];
  const float* lng = (const float*)d_in[19];
  const float* lnb = (const float*)d_in[20];
  const float* Wg = (const float*)d_in[21];
  const float* bg = (const float*)d_in[22];
  const float* W1 = (const float*)d_in[23];
  const float* b1 = (const float*)d_in[24];
  const float* W2 = (const float*)d_in[25];
  const float* b2 = (const float*)d_in[26];
  float* out = (float*)d_out;

  char* w = (char*)d_ws;
  auto carve = [&](size_t bytes) -> char* {
    char* p = w;
    w += (bytes + 255) & ~(size_t)255;
    return p;
  };
  float* HF = (float*)carve((size_t)NFAC * H * 4);
  float* GL = (float*)carve((size_t)NFAC * H * 4);   // split-K partial 0; later GL2(fp16) overlay
  float* CP1 = (float*)carve((size_t)NFAC * H * 4);  // split-K partial 1
  __half* GL2 = (__half*)GL;                         // [NFAC][256] fp16 overlay (fits in GL)
  float* HC = (float*)carve((size_t)NCOMP * H * 4);
  float* EF = (float*)carve((size_t)NEDGE * EDIMP * 4);
  int* OFF = (int*)carve(4100 * 4);
  int* POS = (int*)carve((size_t)NEDGE * 4);
  int* SRCS = (int*)carve((size_t)NEDGE * 4);
  unsigned short* WfH = (unsigned short*)carve((size_t)DF * H * 2);
  unsigned short* WfL = (unsigned short*)carve((size_t)DF * H * 2);
  unsigned short* WlH2 = (unsigned short*)carve((size_t)256 * H * 2);
  unsigned short* WlL2 = (unsigned short*)carve((size_t)256 * H * 2);
  char* zbase = w;
  int* DEG = (int*)carve(4096 * 4);
  int* CUR = (int*)carve(4096 * 4);
  float* PF = (float*)carve((size_t)NB * H * 4);
  float* PC = (float*)carve((size_t)NB * H * 4);
  int* CF = (int*)carve(NB * 4);
  int* CC = (int*)carve(NB * 4);
  size_t zbytes = (size_t)(w - zbase);
  hipMemsetAsync(zbase, 0, zbytes, stream);

  const int* srcArr = eidx;
  const int* dstArr = eidx + NEDGE;

  k_hist<<<(NEDGE + 255) / 256, 256, 0, stream>>>(dstArr, DEG);
  k_scan<<<1, 1024, 0, stream>>>(DEG, OFF);
  k_scatter<<<(NEDGE + 255) / 256, 256, 0, stream>>>(dstArr, srcArr, OFF, CUR, POS, SRCS);
  k_edge_feat<<<(NEDGE + 255) / 256, 256, 0, stream>>>(ea, lam, POS, EF);

  // weight preconvert
  k_conv_w<<<(DF * H + 255) / 256, 256, 0, stream>>>(Wf, WfH, WfL, DF);
  k_conv_wl2<<<(2 * H * H + 255) / 256, 256, 0, stream>>>(Wl, WlH2, WlL2);

  // big encoder GEMM: split-K x2, partials in GL/CP1, then reduce(+bias,+relu) into HF
  {
    float* CPART = GL;  // [2][NFAC][H] with CP1 contiguous after GL
    dim3 grid((NFAC + 127) / 128, 2);
    k_gemm_mfma<<<grid, 256, 0, stream>>>(x_fact, WfH, WfL, bf, HF, NFAC, DF, 1, CPART);
    int total4 = NFAC * H / 4;
    k_reduce2<<<(total4 + 255) / 256, 256, 0, stream>>>(GL, CP1, bf, HF, total4);
  }
  k_enc_comp<<<NCOMP / 2, 256, 0, stream>>>(x_comp, Wc, bc, HC);

  // merged GL GEMM -> fp16 GL2 (overwrites GL; GL/CP1 dead after reduce2)
  k_gemm_n256<<<(NFAC + 63) / 64, 256, 0, stream>>>(HF, WlH2, WlL2, bl, GL2, NFAC);

  for (int l = 0; l < 2; l++) {
    k_node<<<NCOMP, 128, 0, stream>>>(GL2 + l * 128, EF, SRCS, OFF,
                                      Wr + (size_t)l * H * H, br_ + l * H,
                                      We + (size_t)l * EDIM * H, be + l * H, att + l * H,
                                      b_out + l * H, lng + l * H, lnb + l * H, HC);
  }

  k_segmean<128><<<(NFAC + 127) / 128, 128, 0, stream>>>(HF, batf, NFAC, PF, CF);
  k_segmean<64><<<(NCOMP + 63) / 64, 128, 0, stream>>>(HC, batc, NCOMP, PC, CC);
  k_readout<<<NB, 128, 0, stream>>>(PF, PC, CF, CC, Wg, bg, W1, b1, W2, b2, out);
}